// Round 4
// baseline (1774.617 us; speedup 1.0000x reference)
//
#include <hip/hip_runtime.h>

#define EMB_D 64

// ---------------------------------------------------------------------------
// Kernel 1: scatter messages  h[dst[e]] += emb[src[e]] * w[e]
// 16 threads per edge, each thread owns 4 consecutive dims (float4).
// Within a 16-lane group the emb row read is one coalesced 256B segment;
// src/dst/w loads broadcast across the group.
// ---------------------------------------------------------------------------
__global__ void lightgcn_scatter(const float* __restrict__ emb,
                                 const float* __restrict__ w,
                                 const int* __restrict__ src,
                                 const int* __restrict__ dst,
                                 float* __restrict__ h,
                                 int E) {
    long long t = (long long)blockIdx.x * blockDim.x + threadIdx.x;
    int e = (int)(t >> 4);          // edge index
    int d = (int)(t & 15) << 2;     // dim offset (0,4,...,60)
    if (e >= E) return;

    int s = src[e];
    int v = dst[e];
    float wt = w[e];

    const float4 m = *reinterpret_cast<const float4*>(emb + (size_t)s * EMB_D + d);
    float* out = h + (size_t)v * EMB_D + d;

    // unsafeAtomicAdd -> HW global_atomic_add_f32 (no CAS loop) on gfx950.
    unsafeAtomicAdd(out + 0, m.x * wt);
    unsafeAtomicAdd(out + 1, m.y * wt);
    unsafeAtomicAdd(out + 2, m.z * wt);
    unsafeAtomicAdd(out + 3, m.w * wt);
}

// ---------------------------------------------------------------------------
// Kernel 2: in-place L2 row normalization. One wave (64 lanes) per row;
// lane == dim. Butterfly shuffle reduce gives all lanes the full sum.
// ---------------------------------------------------------------------------
__global__ void lightgcn_normalize(float* __restrict__ h, int N) {
    int row = blockIdx.x * (blockDim.x >> 6) + (threadIdx.x >> 6);
    int lane = threadIdx.x & 63;
    if (row >= N) return;

    float x = h[(size_t)row * EMB_D + lane];
    float ss = x * x;
    #pragma unroll
    for (int off = 32; off > 0; off >>= 1)
        ss += __shfl_xor(ss, off, 64);

    float norm = sqrtf(ss);
    float scale = 1.0f / fmaxf(norm, 1e-12f);
    h[(size_t)row * EMB_D + lane] = x * scale;
}

extern "C" void kernel_launch(void* const* d_in, const int* in_sizes, int n_in,
                              void* d_out, int out_size, void* d_ws, size_t ws_size,
                              hipStream_t stream) {
    const float* emb = (const float*)d_in[0];   // [N, 64] fp32
    const float* w   = (const float*)d_in[1];   // [E] fp32
    const int*   src = (const int*)d_in[2];     // [E] int32
    const int*   dst = (const int*)d_in[3];     // [E] int32
    float* out = (float*)d_out;                 // [N, 64] fp32

    const int N = in_sizes[0] / EMB_D;
    const int E = in_sizes[1];

    // d_out is poisoned to 0xAA before every call — zero it (accumulator).
    hipMemsetAsync(d_out, 0, (size_t)out_size * sizeof(float), stream);

    // Scatter: E*16 threads.
    {
        long long total = (long long)E * 16;
        int block = 256;
        int grid = (int)((total + block - 1) / block);
        lightgcn_scatter<<<grid, block, 0, stream>>>(emb, w, src, dst, out, E);
    }

    // Normalize: one wave per row, 4 rows per 256-thread block.
    {
        int rows_per_block = 256 / 64;
        int grid = (N + rows_per_block - 1) / rows_per_block;
        lightgcn_normalize<<<grid, 256, 0, stream>>>(out, N);
    }
}

// Round 5
// 496.766 us; speedup vs baseline: 3.5723x; 3.5723x over previous
//
#include <hip/hip_runtime.h>

#define EMB_D 64
#define SCAN_BLOCK 1024

// ===========================================================================
// Fast path: build dst-bucketed CSR in workspace, then node-centric gather
// with fused L2 normalization. Eliminates all fp32 atomics (128M -> 0);
// only 4M int atomics remain (histogram + bucket cursors).
// ===========================================================================

// --- Phase 1: histogram of dst -------------------------------------------
__global__ void hist_kernel(const int* __restrict__ dst, int* __restrict__ counts,
                            int E) {
    int i = blockIdx.x * blockDim.x + threadIdx.x;
    int stride = gridDim.x * blockDim.x;
    for (; i < E; i += stride)
        atomicAdd(&counts[dst[i]], 1);
}

// --- Phase 2: exclusive prefix scan over N counts (single block) ---------
// offsets[i] = sum(counts[0..i-1]); cursors[] = copy; offsets[N] = E.
__global__ void scan_kernel(const int* __restrict__ counts,
                            int* __restrict__ offsets,
                            int* __restrict__ cursors, int N) {
    __shared__ int wsum[16];
    __shared__ int wpre[16];
    __shared__ int running_s;
    const int tid = threadIdx.x, lane = tid & 63, wid = tid >> 6;
    if (tid == 0) running_s = 0;
    __syncthreads();
    for (int base = 0; base < N; base += SCAN_BLOCK) {
        int i = base + tid;
        int v = (i < N) ? counts[i] : 0;
        int x = v;  // wave-level inclusive scan
        #pragma unroll
        for (int off = 1; off < 64; off <<= 1) {
            int t = __shfl_up(x, off, 64);
            if (lane >= off) x += t;
        }
        if (lane == 63) wsum[wid] = x;
        __syncthreads();
        if (wid == 0) {  // scan the 16 wave totals
            int s = (lane < 16) ? wsum[lane] : 0;
            #pragma unroll
            for (int off = 1; off < 16; off <<= 1) {
                int t = __shfl_up(s, off, 64);
                if (lane >= off) s += t;
            }
            if (lane < 16) wpre[lane] = s;  // inclusive
        }
        __syncthreads();
        int waveoff = (wid > 0) ? wpre[wid - 1] : 0;
        int run = running_s;
        int excl = run + waveoff + (x - v);
        if (i < N) { offsets[i] = excl; cursors[i] = excl; }
        int total = wpre[15];
        __syncthreads();                 // all reads of running_s done
        if (tid == 0) running_s = run + total;
        __syncthreads();                 // visible before next iteration
    }
    if (threadIdx.x == 0) offsets[N] = running_s;
}

// --- Phase 3: scatter edges into dst buckets -----------------------------
__global__ void bucket_kernel(const int* __restrict__ src,
                              const int* __restrict__ dst,
                              const float* __restrict__ w,
                              int* __restrict__ cursors,
                              int2* __restrict__ edata, int E) {
    int i = blockIdx.x * blockDim.x + threadIdx.x;
    int stride = gridDim.x * blockDim.x;
    for (; i < E; i += stride) {
        int v = dst[i];
        int slot = atomicAdd(&cursors[v], 1);
        edata[slot] = make_int2(src[i], __float_as_int(w[i]));
    }
}

// --- Phase 4: node-centric gather + fused L2 normalize -------------------
// One wave per node; lane = dim. Edges staged 64-at-a-time with one
// coalesced int2 load, then broadcast via shuffle.
__global__ void gather_norm_kernel(const float* __restrict__ emb,
                                   const int* __restrict__ offsets,
                                   const int2* __restrict__ edata,
                                   float* __restrict__ out, int N) {
    int node = blockIdx.x * (blockDim.x >> 6) + (threadIdx.x >> 6);
    int lane = threadIdx.x & 63;
    if (node >= N) return;

    int beg = offsets[node];
    int end = offsets[node + 1];

    float acc = 0.0f;
    for (int b = beg; b < end; b += 64) {
        int n = min(64, end - b);
        int es = 0; int ew = 0;
        if (lane < n) { int2 e = edata[b + lane]; es = e.x; ew = e.y; }
        for (int j = 0; j < n; ++j) {
            int   s  = __shfl(es, j, 64);
            float wt = __int_as_float(__shfl(ew, j, 64));
            acc = fmaf(emb[(size_t)s * EMB_D + lane], wt, acc);
        }
    }

    // fused F.normalize: x / max(||x||, eps)
    float ss = acc * acc;
    #pragma unroll
    for (int off = 32; off > 0; off >>= 1)
        ss += __shfl_xor(ss, off, 64);
    float scale = 1.0f / fmaxf(sqrtf(ss), 1e-12f);
    out[(size_t)node * EMB_D + lane] = acc * scale;
}

// ===========================================================================
// Fallback path (proven correct, ~1.77 ms): direct atomic scatter.
// Used only if ws_size can't hold the CSR (needs ~17 MB).
// ===========================================================================
__global__ void lightgcn_scatter(const float* __restrict__ emb,
                                 const float* __restrict__ w,
                                 const int* __restrict__ src,
                                 const int* __restrict__ dst,
                                 float* __restrict__ h, int E) {
    long long t = (long long)blockIdx.x * blockDim.x + threadIdx.x;
    int e = (int)(t >> 4);
    int d = (int)(t & 15) << 2;
    if (e >= E) return;
    int s = src[e]; int v = dst[e]; float wt = w[e];
    const float4 m = *reinterpret_cast<const float4*>(emb + (size_t)s * EMB_D + d);
    float* o = h + (size_t)v * EMB_D + d;
    unsafeAtomicAdd(o + 0, m.x * wt);
    unsafeAtomicAdd(o + 1, m.y * wt);
    unsafeAtomicAdd(o + 2, m.z * wt);
    unsafeAtomicAdd(o + 3, m.w * wt);
}

__global__ void lightgcn_normalize(float* __restrict__ h, int N) {
    int row = blockIdx.x * (blockDim.x >> 6) + (threadIdx.x >> 6);
    int lane = threadIdx.x & 63;
    if (row >= N) return;
    float x = h[(size_t)row * EMB_D + lane];
    float ss = x * x;
    #pragma unroll
    for (int off = 32; off > 0; off >>= 1)
        ss += __shfl_xor(ss, off, 64);
    h[(size_t)row * EMB_D + lane] = x / fmaxf(sqrtf(ss), 1e-12f);
}

extern "C" void kernel_launch(void* const* d_in, const int* in_sizes, int n_in,
                              void* d_out, int out_size, void* d_ws, size_t ws_size,
                              hipStream_t stream) {
    const float* emb = (const float*)d_in[0];   // [N, 64] fp32
    const float* w   = (const float*)d_in[1];   // [E] fp32
    const int*   src = (const int*)d_in[2];     // [E] int32
    const int*   dst = (const int*)d_in[3];     // [E] int32
    float* out = (float*)d_out;

    const int N = in_sizes[0] / EMB_D;
    const int E = in_sizes[1];

    // Workspace layout: counts[N] | offsets[N+1] | cursors[N] | pad | edata[E] (int2)
    size_t ints_bytes  = (size_t)(3 * N + 1) * sizeof(int);
    size_t edata_off   = (ints_bytes + 15) & ~(size_t)15;   // 16B align
    size_t needed      = edata_off + (size_t)E * sizeof(int2);

    if (ws_size >= needed) {
        char* ws = (char*)d_ws;
        int*  counts  = (int*)ws;
        int*  offsets = counts + N;
        int*  cursors = offsets + N + 1;
        int2* edata   = (int2*)(ws + edata_off);

        hipMemsetAsync(counts, 0, (size_t)N * sizeof(int), stream);

        int block = 256;
        int gridE = (E + block - 1) / block;
        hist_kernel<<<gridE, block, 0, stream>>>(dst, counts, E);
        scan_kernel<<<1, SCAN_BLOCK, 0, stream>>>(counts, offsets, cursors, N);
        bucket_kernel<<<gridE, block, 0, stream>>>(src, dst, w, cursors, edata, E);

        int rows_per_block = 256 / 64;
        int gridN = (N + rows_per_block - 1) / rows_per_block;
        gather_norm_kernel<<<gridN, 256, 0, stream>>>(emb, offsets, edata, out, N);
    } else {
        // Fallback: atomic scatter (needs zeroed output accumulator).
        hipMemsetAsync(d_out, 0, (size_t)out_size * sizeof(float), stream);
        long long total = (long long)E * 16;
        int block = 256;
        int grid = (int)((total + block - 1) / block);
        lightgcn_scatter<<<grid, block, 0, stream>>>(emb, w, src, dst, out, E);
        int rows_per_block = 256 / 64;
        int gridN = (N + rows_per_block - 1) / rows_per_block;
        lightgcn_normalize<<<gridN, 256, 0, stream>>>(out, N);
    }
}

// Round 6
// 430.410 us; speedup vs baseline: 4.1231x; 1.1542x over previous
//
#include <hip/hip_runtime.h>

#define EMB_D 64
#define SB 1024   // scan block size

// ===========================================================================
// Pipeline: hist -> 3-phase scan -> bucket (CSR) -> gather + fused normalize
// ===========================================================================

// --- Phase 1: histogram of dst -------------------------------------------
__global__ void hist_kernel(const int* __restrict__ dst, int* __restrict__ counts,
                            int E) {
    int i = blockIdx.x * blockDim.x + threadIdx.x;
    int stride = gridDim.x * blockDim.x;
    for (; i < E; i += stride)
        atomicAdd(&counts[dst[i]], 1);
}

// --- Phase 2a: per-block sums of counts ----------------------------------
__global__ void scan_reduce(const int* __restrict__ counts,
                            int* __restrict__ partial, int N) {
    __shared__ int wsum[16];
    const int tid = threadIdx.x, lane = tid & 63, wid = tid >> 6;
    int i = blockIdx.x * SB + tid;
    int v = (i < N) ? counts[i] : 0;
    #pragma unroll
    for (int off = 32; off > 0; off >>= 1)
        v += __shfl_xor(v, off, 64);
    if (lane == 0) wsum[wid] = v;
    __syncthreads();
    if (tid == 0) {
        int s = 0;
        #pragma unroll
        for (int k = 0; k < 16; ++k) s += wsum[k];
        partial[blockIdx.x] = s;
    }
}

// --- Phase 2b: exclusive scan of block partials (numB <= 1024) -----------
__global__ void scan_partials(const int* __restrict__ partial,
                              int* __restrict__ blockoff,
                              int* __restrict__ offsets, int numB, int N) {
    __shared__ int wsum[16];
    __shared__ int wpre[16];
    const int tid = threadIdx.x, lane = tid & 63, wid = tid >> 6;
    int v = (tid < numB) ? partial[tid] : 0;
    int x = v;
    #pragma unroll
    for (int off = 1; off < 64; off <<= 1) {
        int t = __shfl_up(x, off, 64);
        if (lane >= off) x += t;
    }
    if (lane == 63) wsum[wid] = x;
    __syncthreads();
    if (wid == 0) {
        int s = (lane < 16) ? wsum[lane] : 0;
        #pragma unroll
        for (int off = 1; off < 16; off <<= 1) {
            int t = __shfl_up(s, off, 64);
            if (lane >= off) s += t;
        }
        if (lane < 16) wpre[lane] = s;
    }
    __syncthreads();
    int excl = ((wid > 0) ? wpre[wid - 1] : 0) + (x - v);
    if (tid < numB) blockoff[tid] = excl;
    if (tid == 0) offsets[N] = wpre[15];   // grand total = E
}

// --- Phase 2c: per-block exclusive scan + apply block offset -------------
__global__ void scan_apply(const int* __restrict__ counts,
                           const int* __restrict__ blockoff,
                           int* __restrict__ offsets,
                           int* __restrict__ cursors, int N) {
    __shared__ int wsum[16];
    __shared__ int wpre[16];
    const int tid = threadIdx.x, lane = tid & 63, wid = tid >> 6;
    int i = blockIdx.x * SB + tid;
    int v = (i < N) ? counts[i] : 0;
    int x = v;
    #pragma unroll
    for (int off = 1; off < 64; off <<= 1) {
        int t = __shfl_up(x, off, 64);
        if (lane >= off) x += t;
    }
    if (lane == 63) wsum[wid] = x;
    __syncthreads();
    if (wid == 0) {
        int s = (lane < 16) ? wsum[lane] : 0;
        #pragma unroll
        for (int off = 1; off < 16; off <<= 1) {
            int t = __shfl_up(s, off, 64);
            if (lane >= off) s += t;
        }
        if (lane < 16) wpre[lane] = s;
    }
    __syncthreads();
    int excl = blockoff[blockIdx.x] + ((wid > 0) ? wpre[wid - 1] : 0) + (x - v);
    if (i < N) { offsets[i] = excl; cursors[i] = excl; }
}

// --- Phase 3: scatter edges into dst buckets -----------------------------
__global__ void bucket_kernel(const int* __restrict__ src,
                              const int* __restrict__ dst,
                              const float* __restrict__ w,
                              int* __restrict__ cursors,
                              int2* __restrict__ edata, int E) {
    int i = blockIdx.x * blockDim.x + threadIdx.x;
    int stride = gridDim.x * blockDim.x;
    for (; i < E; i += stride) {
        int v = dst[i];
        int slot = atomicAdd(&cursors[v], 1);
        edata[slot] = make_int2(src[i], __float_as_int(w[i]));
    }
}

// --- Phase 4: node-centric gather + fused L2 normalize -------------------
__global__ void gather_norm_kernel(const float* __restrict__ emb,
                                   const int* __restrict__ offsets,
                                   const int2* __restrict__ edata,
                                   float* __restrict__ out, int N) {
    int node = blockIdx.x * (blockDim.x >> 6) + (threadIdx.x >> 6);
    int lane = threadIdx.x & 63;
    if (node >= N) return;

    int beg = offsets[node];
    int end = offsets[node + 1];

    float acc = 0.0f;
    for (int b = beg; b < end; b += 64) {
        int n = min(64, end - b);
        int es = 0; int ew = 0;
        if (lane < n) { int2 e = edata[b + lane]; es = e.x; ew = e.y; }
        for (int j = 0; j < n; ++j) {
            int   s  = __shfl(es, j, 64);
            float wt = __int_as_float(__shfl(ew, j, 64));
            acc = fmaf(emb[(size_t)s * EMB_D + lane], wt, acc);
        }
    }

    float ss = acc * acc;
    #pragma unroll
    for (int off = 32; off > 0; off >>= 1)
        ss += __shfl_xor(ss, off, 64);
    float scale = 1.0f / fmaxf(sqrtf(ss), 1e-12f);
    out[(size_t)node * EMB_D + lane] = acc * scale;
}

// ===========================================================================
// Fallback path: direct atomic scatter (used only if ws too small).
// ===========================================================================
__global__ void lightgcn_scatter(const float* __restrict__ emb,
                                 const float* __restrict__ w,
                                 const int* __restrict__ src,
                                 const int* __restrict__ dst,
                                 float* __restrict__ h, int E) {
    long long t = (long long)blockIdx.x * blockDim.x + threadIdx.x;
    int e = (int)(t >> 4);
    int d = (int)(t & 15) << 2;
    if (e >= E) return;
    int s = src[e]; int v = dst[e]; float wt = w[e];
    const float4 m = *reinterpret_cast<const float4*>(emb + (size_t)s * EMB_D + d);
    float* o = h + (size_t)v * EMB_D + d;
    unsafeAtomicAdd(o + 0, m.x * wt);
    unsafeAtomicAdd(o + 1, m.y * wt);
    unsafeAtomicAdd(o + 2, m.z * wt);
    unsafeAtomicAdd(o + 3, m.w * wt);
}

__global__ void lightgcn_normalize(float* __restrict__ h, int N) {
    int row = blockIdx.x * (blockDim.x >> 6) + (threadIdx.x >> 6);
    int lane = threadIdx.x & 63;
    if (row >= N) return;
    float x = h[(size_t)row * EMB_D + lane];
    float ss = x * x;
    #pragma unroll
    for (int off = 32; off > 0; off >>= 1)
        ss += __shfl_xor(ss, off, 64);
    h[(size_t)row * EMB_D + lane] = x / fmaxf(sqrtf(ss), 1e-12f);
}

extern "C" void kernel_launch(void* const* d_in, const int* in_sizes, int n_in,
                              void* d_out, int out_size, void* d_ws, size_t ws_size,
                              hipStream_t stream) {
    const float* emb = (const float*)d_in[0];   // [N, 64] fp32
    const float* w   = (const float*)d_in[1];   // [E] fp32
    const int*   src = (const int*)d_in[2];     // [E] int32
    const int*   dst = (const int*)d_in[3];     // [E] int32
    float* out = (float*)d_out;

    const int N = in_sizes[0] / EMB_D;
    const int E = in_sizes[1];
    const int numB = (N + SB - 1) / SB;         // scan blocks (<= 1024 for N <= 1M)

    // Workspace: counts[N] | offsets[N+1] | cursors[N] | partial[numB] |
    //            blockoff[numB] | pad16 | edata[E] (int2)
    size_t ints = (size_t)(3 * N + 1 + 2 * numB) * sizeof(int);
    size_t edata_off = (ints + 15) & ~(size_t)15;
    size_t needed = edata_off + (size_t)E * sizeof(int2);

    if (ws_size >= needed && numB <= 1024) {
        char* ws = (char*)d_ws;
        int*  counts   = (int*)ws;
        int*  offsets  = counts + N;
        int*  cursors  = offsets + N + 1;
        int*  partial  = cursors + N;
        int*  blockoff = partial + numB;
        int2* edata    = (int2*)(ws + edata_off);

        hipMemsetAsync(counts, 0, (size_t)N * sizeof(int), stream);

        int block = 256;
        int gridE = (E + block - 1) / block;
        hist_kernel<<<gridE, block, 0, stream>>>(dst, counts, E);
        scan_reduce<<<numB, SB, 0, stream>>>(counts, partial, N);
        scan_partials<<<1, SB, 0, stream>>>(partial, blockoff, offsets, numB, N);
        scan_apply<<<numB, SB, 0, stream>>>(counts, blockoff, offsets, cursors, N);
        bucket_kernel<<<gridE, block, 0, stream>>>(src, dst, w, cursors, edata, E);

        int rows_per_block = 256 / 64;
        int gridN = (N + rows_per_block - 1) / rows_per_block;
        gather_norm_kernel<<<gridN, 256, 0, stream>>>(emb, offsets, edata, out, N);
    } else {
        hipMemsetAsync(d_out, 0, (size_t)out_size * sizeof(float), stream);
        long long total = (long long)E * 16;
        int block = 256;
        int grid = (int)((total + block - 1) / block);
        lightgcn_scatter<<<grid, block, 0, stream>>>(emb, w, src, dst, out, E);
        int rows_per_block = 256 / 64;
        int gridN = (N + rows_per_block - 1) / rows_per_block;
        lightgcn_normalize<<<gridN, 256, 0, stream>>>(out, N);
    }
}

// Round 7
// 334.601 us; speedup vs baseline: 5.3037x; 1.2863x over previous
//
#include <hip/hip_runtime.h>

#define EMB_D 64
#define SB 1024   // scan block size

// ===========================================================================
// Pipeline: hist(+ranks) -> 3-phase scan -> XCD-affinity bucket (CSR of
// edge-ids, no atomics) -> gather + fused L2 normalize
// ===========================================================================

// --- Phase 1: histogram of dst; also record each edge's rank within node --
__global__ void hist_kernel(const int* __restrict__ dst, int* __restrict__ counts,
                            int* __restrict__ ranks, int E) {
    int i = blockIdx.x * blockDim.x + threadIdx.x;
    int stride = gridDim.x * blockDim.x;
    for (; i < E; i += stride)
        ranks[i] = atomicAdd(&counts[dst[i]], 1);
}

// --- Phase 2a: per-block sums of counts ----------------------------------
__global__ void scan_reduce(const int* __restrict__ counts,
                            int* __restrict__ partial, int N) {
    __shared__ int wsum[16];
    const int tid = threadIdx.x, lane = tid & 63, wid = tid >> 6;
    int i = blockIdx.x * SB + tid;
    int v = (i < N) ? counts[i] : 0;
    #pragma unroll
    for (int off = 32; off > 0; off >>= 1)
        v += __shfl_xor(v, off, 64);
    if (lane == 0) wsum[wid] = v;
    __syncthreads();
    if (tid == 0) {
        int s = 0;
        #pragma unroll
        for (int k = 0; k < 16; ++k) s += wsum[k];
        partial[blockIdx.x] = s;
    }
}

// --- Phase 2b: exclusive scan of block partials (numB <= 1024) -----------
__global__ void scan_partials(const int* __restrict__ partial,
                              int* __restrict__ blockoff,
                              int* __restrict__ offsets, int numB, int N) {
    __shared__ int wsum[16];
    __shared__ int wpre[16];
    const int tid = threadIdx.x, lane = tid & 63, wid = tid >> 6;
    int v = (tid < numB) ? partial[tid] : 0;
    int x = v;
    #pragma unroll
    for (int off = 1; off < 64; off <<= 1) {
        int t = __shfl_up(x, off, 64);
        if (lane >= off) x += t;
    }
    if (lane == 63) wsum[wid] = x;
    __syncthreads();
    if (wid == 0) {
        int s = (lane < 16) ? wsum[lane] : 0;
        #pragma unroll
        for (int off = 1; off < 16; off <<= 1) {
            int t = __shfl_up(s, off, 64);
            if (lane >= off) s += t;
        }
        if (lane < 16) wpre[lane] = s;
    }
    __syncthreads();
    int excl = ((wid > 0) ? wpre[wid - 1] : 0) + (x - v);
    if (tid < numB) blockoff[tid] = excl;
    if (tid == 0) offsets[N] = wpre[15];   // grand total = E
}

// --- Phase 2c: per-block exclusive scan + apply block offset -------------
__global__ void scan_apply(const int* __restrict__ counts,
                           const int* __restrict__ blockoff,
                           int* __restrict__ offsets, int N) {
    __shared__ int wsum[16];
    __shared__ int wpre[16];
    const int tid = threadIdx.x, lane = tid & 63, wid = tid >> 6;
    int i = blockIdx.x * SB + tid;
    int v = (i < N) ? counts[i] : 0;
    int x = v;
    #pragma unroll
    for (int off = 1; off < 64; off <<= 1) {
        int t = __shfl_up(x, off, 64);
        if (lane >= off) x += t;
    }
    if (lane == 63) wsum[wid] = x;
    __syncthreads();
    if (wid == 0) {
        int s = (lane < 16) ? wsum[lane] : 0;
        #pragma unroll
        for (int off = 1; off < 16; off <<= 1) {
            int t = __shfl_up(s, off, 64);
            if (lane >= off) s += t;
        }
        if (lane < 16) wpre[lane] = s;
    }
    __syncthreads();
    int excl = blockoff[blockIdx.x] + ((wid > 0) ? wpre[wid - 1] : 0) + (x - v);
    if (i < N) offsets[i] = excl;
}

// --- Phase 3: XCD-affinity bucket scatter (no atomics) -------------------
// 8 coverage groups; block's group = blockIdx>>3, its XCD slice = blockIdx&7
// (round-robin block->XCD heuristic). All stores into a node's CSR region
// issue from one XCD -> full-line write combining in that XCD's private L2.
__global__ void bucket_kernel(const int* __restrict__ dst,
                              const int* __restrict__ ranks,
                              const int* __restrict__ offsets,
                              int* __restrict__ eids, int E, int span) {
    int xcd = blockIdx.x & 7;
    int g   = blockIdx.x >> 3;
    int lo = xcd * span;
    int hi = lo + span;
    int stride = (gridDim.x >> 3) * blockDim.x;
    for (int i = g * blockDim.x + threadIdx.x; i < E; i += stride) {
        int v = dst[i];
        if (v >= lo && v < hi)
            eids[offsets[v] + ranks[i]] = i;
    }
}

// --- Phase 4: node-centric gather + fused L2 normalize -------------------
// One wave per node (4 nodes / 256-thr block); lane = dim. Edge metadata is
// wave-uniform (1 tx per load); unroll x4 with 4 accumulators for ILP.
__global__ __launch_bounds__(256) void gather_norm_kernel(
        const float* __restrict__ emb,
        const int* __restrict__ offsets,
        const int* __restrict__ eids,
        const int* __restrict__ src,
        const float* __restrict__ w,
        float* __restrict__ out, int N) {
    int node = blockIdx.x * 4 + (threadIdx.x >> 6);
    int lane = threadIdx.x & 63;
    if (node >= N) return;

    int beg = offsets[node];
    int end = offsets[node + 1];

    float a0 = 0.f, a1 = 0.f, a2 = 0.f, a3 = 0.f;
    int j = beg;
    for (; j + 4 <= end; j += 4) {
        int e0 = eids[j + 0], e1 = eids[j + 1];
        int e2 = eids[j + 2], e3 = eids[j + 3];
        int s0 = src[e0], s1 = src[e1], s2 = src[e2], s3 = src[e3];
        float w0 = w[e0], w1 = w[e1], w2 = w[e2], w3 = w[e3];
        a0 = fmaf(emb[(size_t)s0 * EMB_D + lane], w0, a0);
        a1 = fmaf(emb[(size_t)s1 * EMB_D + lane], w1, a1);
        a2 = fmaf(emb[(size_t)s2 * EMB_D + lane], w2, a2);
        a3 = fmaf(emb[(size_t)s3 * EMB_D + lane], w3, a3);
    }
    for (; j < end; ++j) {
        int e = eids[j];
        a0 = fmaf(emb[(size_t)src[e] * EMB_D + lane], w[e], a0);
    }
    float acc = (a0 + a1) + (a2 + a3);

    float ss = acc * acc;
    #pragma unroll
    for (int off = 32; off > 0; off >>= 1)
        ss += __shfl_xor(ss, off, 64);
    float scale = 1.0f / fmaxf(sqrtf(ss), 1e-12f);
    out[(size_t)node * EMB_D + lane] = acc * scale;
}

// ===========================================================================
// Fallback path: direct atomic scatter (used only if ws too small).
// ===========================================================================
__global__ void lightgcn_scatter(const float* __restrict__ emb,
                                 const float* __restrict__ w,
                                 const int* __restrict__ src,
                                 const int* __restrict__ dst,
                                 float* __restrict__ h, int E) {
    long long t = (long long)blockIdx.x * blockDim.x + threadIdx.x;
    int e = (int)(t >> 4);
    int d = (int)(t & 15) << 2;
    if (e >= E) return;
    int s = src[e]; int v = dst[e]; float wt = w[e];
    const float4 m = *reinterpret_cast<const float4*>(emb + (size_t)s * EMB_D + d);
    float* o = h + (size_t)v * EMB_D + d;
    unsafeAtomicAdd(o + 0, m.x * wt);
    unsafeAtomicAdd(o + 1, m.y * wt);
    unsafeAtomicAdd(o + 2, m.z * wt);
    unsafeAtomicAdd(o + 3, m.w * wt);
}

__global__ void lightgcn_normalize(float* __restrict__ h, int N) {
    int row = blockIdx.x * (blockDim.x >> 6) + (threadIdx.x >> 6);
    int lane = threadIdx.x & 63;
    if (row >= N) return;
    float x = h[(size_t)row * EMB_D + lane];
    float ss = x * x;
    #pragma unroll
    for (int off = 32; off > 0; off >>= 1)
        ss += __shfl_xor(ss, off, 64);
    h[(size_t)row * EMB_D + lane] = x / fmaxf(sqrtf(ss), 1e-12f);
}

extern "C" void kernel_launch(void* const* d_in, const int* in_sizes, int n_in,
                              void* d_out, int out_size, void* d_ws, size_t ws_size,
                              hipStream_t stream) {
    const float* emb = (const float*)d_in[0];   // [N, 64] fp32
    const float* w   = (const float*)d_in[1];   // [E] fp32
    const int*   src = (const int*)d_in[2];     // [E] int32
    const int*   dst = (const int*)d_in[3];     // [E] int32
    float* out = (float*)d_out;

    const int N = in_sizes[0] / EMB_D;
    const int E = in_sizes[1];
    const int numB = (N + SB - 1) / SB;

    // Workspace: counts[N] | offsets[N+1] | partial[numB] | blockoff[numB] |
    //            ranks[E] | eids[E]
    size_t needed = (size_t)(2 * N + 1 + 2 * numB + 2 * E) * sizeof(int);

    if (ws_size >= needed && numB <= 1024) {
        int* counts   = (int*)d_ws;
        int* offsets  = counts + N;
        int* partial  = offsets + N + 1;
        int* blockoff = partial + numB;
        int* ranks    = blockoff + numB;
        int* eids     = ranks + E;

        hipMemsetAsync(counts, 0, (size_t)N * sizeof(int), stream);

        int block = 256;
        int gridE = (E + block - 1) / block;
        hist_kernel<<<gridE, block, 0, stream>>>(dst, counts, ranks, E);
        scan_reduce<<<numB, SB, 0, stream>>>(counts, partial, N);
        scan_partials<<<1, SB, 0, stream>>>(partial, blockoff, offsets, numB, N);
        scan_apply<<<numB, SB, 0, stream>>>(counts, blockoff, offsets, N);

        int span = (N + 7) / 8;
        bucket_kernel<<<8 * 256, block, 0, stream>>>(dst, ranks, offsets, eids, E, span);

        int gridN = (N + 3) / 4;
        gather_norm_kernel<<<gridN, 256, 0, stream>>>(emb, offsets, eids, src, w, out, N);
    } else {
        hipMemsetAsync(d_out, 0, (size_t)out_size * sizeof(float), stream);
        long long total = (long long)E * 16;
        int block = 256;
        int grid = (int)((total + block - 1) / block);
        lightgcn_scatter<<<grid, block, 0, stream>>>(emb, w, src, dst, out, E);
        int gridN = (N + 3) / 4;
        lightgcn_normalize<<<gridN, 256, 0, stream>>>(out, N);
    }
}